// Round 1
// baseline (3284.808 us; speedup 1.0000x reference)
//
#include <hip/hip_runtime.h>
#include <math.h>

#define T_STEPS 30
#define BATCH   64
#define HID     1024
#define VOCABN  32000
#define G3      3072
#define ROWS    (T_STEPS * BATCH)   // 1920
#define OUT_HID_OFF (BATCH * T_STEPS * VOCABN)  // 61,440,000

// workspace layout (in floats)
#define WS_X   0
#define WS_GI  (WS_X  + ROWS * HID)        // 1,966,080
#define WS_H   (WS_GI + ROWS * G3)         // +5,898,240
#define WS_HT0 (WS_H  + ROWS * HID)        // +1,966,080
#define WS_HT1 (WS_HT0 + HID * BATCH)      // +65,536

// ---------------------------------------------------------------- K0: h0 -> hT[k][b]
__global__ __launch_bounds__(256) void transpose_h0(const float* __restrict__ h0,
                                                    float* __restrict__ hT) {
    int idx = blockIdx.x * 256 + threadIdx.x;   // 0..65535
    int k = idx >> 6, b = idx & 63;
    hT[idx] = h0[b * HID + k];
}

// ---------------------------------------------------------------- K1: X = relu(emb[tok])
__global__ __launch_bounds__(256) void embed_relu(const int* __restrict__ target,
                                                  const float* __restrict__ emb,
                                                  float* __restrict__ X) {
    int bid = blockIdx.x;           // t*64 + b
    int t = bid >> 6, b = bid & 63;
    int tok = (t == 0) ? 0 : target[b * T_STEPS + (t - 1)];
    const float4* src = (const float4*)(emb + (size_t)tok * HID);
    float4* dst = (float4*)(X + (size_t)bid * HID);
    float4 v = src[threadIdx.x];
    v.x = fmaxf(v.x, 0.f); v.y = fmaxf(v.y, 0.f);
    v.z = fmaxf(v.z, 0.f); v.w = fmaxf(v.w, 0.f);
    dst[threadIdx.x] = v;
}

// ---------------------------------------------------------------- K2/K4: C = A @ W^T + bias
// A [M][K] row-major, W [N][K] row-major. mode 0: out[row][col] row-major [M][N].
// mode 1: row = t*64+b -> out[(b*30+t)*32000 + col]  (logits into d_out)
#define BM 128
#define BN 128
#define BKK 16
__global__ __launch_bounds__(256) void gemm_bias(const float* __restrict__ A,
                                                 const float* __restrict__ W,
                                                 const float* __restrict__ bias,
                                                 float* __restrict__ out,
                                                 int M, int N, int K, int mode) {
    __shared__ __attribute__((aligned(16))) float As[BKK][132];
    __shared__ __attribute__((aligned(16))) float Bs[BKK][132];
    int tid = threadIdx.x;
    int tx = tid & 15, ty = tid >> 4;
    int lr = tid >> 1;            // 0..127 tile row
    int lk = (tid & 1) * 8;       // 0 or 8
    const float* Ag = A + ((size_t)blockIdx.y * BM + lr) * (size_t)K + lk;
    const float* Wg = W + ((size_t)blockIdx.x * BN + lr) * (size_t)K + lk;

    float acc[8][8];
#pragma unroll
    for (int i = 0; i < 8; ++i)
#pragma unroll
        for (int j = 0; j < 8; ++j) acc[i][j] = 0.f;

    for (int kt = 0; kt < K; kt += BKK) {
        float4 a0 = *(const float4*)(Ag + kt);
        float4 a1 = *(const float4*)(Ag + kt + 4);
        float4 b0 = *(const float4*)(Wg + kt);
        float4 b1 = *(const float4*)(Wg + kt + 4);
        __syncthreads();
        As[lk + 0][lr] = a0.x; As[lk + 1][lr] = a0.y; As[lk + 2][lr] = a0.z; As[lk + 3][lr] = a0.w;
        As[lk + 4][lr] = a1.x; As[lk + 5][lr] = a1.y; As[lk + 6][lr] = a1.z; As[lk + 7][lr] = a1.w;
        Bs[lk + 0][lr] = b0.x; Bs[lk + 1][lr] = b0.y; Bs[lk + 2][lr] = b0.z; Bs[lk + 3][lr] = b0.w;
        Bs[lk + 4][lr] = b1.x; Bs[lk + 5][lr] = b1.y; Bs[lk + 6][lr] = b1.z; Bs[lk + 7][lr] = b1.w;
        __syncthreads();
#pragma unroll
        for (int kk = 0; kk < BKK; ++kk) {
            float4 aLo = *(const float4*)&As[kk][ty * 8];
            float4 aHi = *(const float4*)&As[kk][ty * 8 + 4];
            float4 bLo = *(const float4*)&Bs[kk][tx * 8];
            float4 bHi = *(const float4*)&Bs[kk][tx * 8 + 4];
            float av[8] = {aLo.x, aLo.y, aLo.z, aLo.w, aHi.x, aHi.y, aHi.z, aHi.w};
            float bv[8] = {bLo.x, bLo.y, bLo.z, bLo.w, bHi.x, bHi.y, bHi.z, bHi.w};
#pragma unroll
            for (int i = 0; i < 8; ++i)
#pragma unroll
                for (int j = 0; j < 8; ++j) acc[i][j] += av[i] * bv[j];
        }
    }

#pragma unroll
    for (int i = 0; i < 8; ++i) {
        int gr = blockIdx.y * BM + ty * 8 + i;
#pragma unroll
        for (int j = 0; j < 8; ++j) {
            int gc = blockIdx.x * BN + tx * 8 + j;
            float v = acc[i][j] + bias[gc];
            if (mode == 0) {
                out[(size_t)gr * N + gc] = v;
            } else {
                int t = gr >> 6, b = gr & 63;
                out[((size_t)b * T_STEPS + t) * VOCABN + gc] = v;
            }
        }
    }
}

// ---------------------------------------------------------------- K3: one GRU step
// grid 256 blocks x 256 threads; wave w handles m = bid*4+w for all 64 b (lane=b)
__global__ __launch_bounds__(256) void gru_step(const float* __restrict__ hT_cur,
                                                float* __restrict__ hT_next,
                                                const float* __restrict__ w_hh,
                                                const float* __restrict__ b_hh,
                                                const float* __restrict__ gi_t,
                                                float* __restrict__ H_all_t,
                                                float* __restrict__ h_final_out) {
    __shared__ float sh[128 * 64];   // 32 KB chunk of hT
    int tid = threadIdx.x;
    int lane = tid & 63;
    int w = tid >> 6;
    int m = __builtin_amdgcn_readfirstlane(blockIdx.x * 4 + w);
    const float* wr_p = w_hh + (size_t)m * HID;
    const float* wz_p = w_hh + (size_t)(HID + m) * HID;
    const float* wn_p = w_hh + (size_t)(2 * HID + m) * HID;
    float accr = 0.f, accz = 0.f, accn = 0.f;

    for (int c = 0; c < 8; ++c) {
        __syncthreads();
        const float4* src = (const float4*)(hT_cur + c * 8192);
        float4* dst = (float4*)sh;
#pragma unroll
        for (int q = 0; q < 8; ++q) dst[q * 256 + tid] = src[q * 256 + tid];
        __syncthreads();
        int kbase = c * 128;
#pragma unroll 4
        for (int k = 0; k < 128; ++k) {
            float hv = sh[k * 64 + lane];
            accr += hv * wr_p[kbase + k];
            accz += hv * wz_p[kbase + k];
            accn += hv * wn_p[kbase + k];
        }
    }

    int b = lane;
    const float* gi = gi_t + (size_t)b * G3;
    float ir = gi[m], iz = gi[HID + m], in_ = gi[2 * HID + m];
    float hr = accr + b_hh[m];
    float hz = accz + b_hh[HID + m];
    float hn = accn + b_hh[2 * HID + m];
    float r = 1.0f / (1.0f + expf(-(ir + hr)));
    float z = 1.0f / (1.0f + expf(-(iz + hz)));
    float n = tanhf(in_ + r * hn);
    float hp = hT_cur[(size_t)m * 64 + lane];
    float hnew = (1.0f - z) * n + z * hp;
    hT_next[(size_t)m * 64 + lane] = hnew;
    H_all_t[(size_t)b * HID + m] = hnew;
    if (h_final_out) h_final_out[(size_t)b * HID + m] = hnew;
}

// ---------------------------------------------------------------- K5: in-place log_softmax per row
__global__ __launch_bounds__(256) void log_softmax_rows(float* __restrict__ out) {
    float* p = out + (size_t)blockIdx.x * VOCABN;
    int tid = threadIdx.x;
    int lane = tid & 63, w = tid >> 6;
    __shared__ float redm[4], reds[4], bcast[2];

    float m = -1e30f;
    for (int i = tid; i < VOCABN; i += 256) m = fmaxf(m, p[i]);
#pragma unroll
    for (int off = 32; off > 0; off >>= 1) m = fmaxf(m, __shfl_down(m, off, 64));
    if (lane == 0) redm[w] = m;
    __syncthreads();
    if (tid == 0) bcast[0] = fmaxf(fmaxf(redm[0], redm[1]), fmaxf(redm[2], redm[3]));
    __syncthreads();
    float mx = bcast[0];

    float s = 0.f;
    for (int i = tid; i < VOCABN; i += 256) s += expf(p[i] - mx);
#pragma unroll
    for (int off = 32; off > 0; off >>= 1) s += __shfl_down(s, off, 64);
    if (lane == 0) reds[w] = s;
    __syncthreads();
    if (tid == 0) bcast[1] = logf(reds[0] + reds[1] + reds[2] + reds[3]);
    __syncthreads();
    float lg = bcast[1];

    for (int i = tid; i < VOCABN; i += 256) p[i] = p[i] - mx - lg;
}

// ----------------------------------------------------------------
extern "C" void kernel_launch(void* const* d_in, const int* in_sizes, int n_in,
                              void* d_out, int out_size, void* d_ws, size_t ws_size,
                              hipStream_t stream) {
    const float* enc_h  = (const float*)d_in[1];
    const int*   target = (const int*)d_in[2];
    const float* emb    = (const float*)d_in[3];
    const float* w_ih   = (const float*)d_in[4];
    const float* w_hh   = (const float*)d_in[5];
    const float* b_ih   = (const float*)d_in[6];
    const float* b_hh   = (const float*)d_in[7];
    const float* out_w  = (const float*)d_in[8];
    const float* out_b  = (const float*)d_in[9];
    float* out = (float*)d_out;
    float* ws  = (float*)d_ws;

    float* X    = ws + WS_X;
    float* gi   = ws + WS_GI;
    float* Hall = ws + WS_H;
    float* hT0  = ws + WS_HT0;
    float* hT1  = ws + WS_HT1;

    transpose_h0<<<256, 256, 0, stream>>>(enc_h, hT0);
    embed_relu<<<ROWS, 256, 0, stream>>>(target, emb, X);
    gemm_bias<<<dim3(G3 / BN, ROWS / BM), 256, 0, stream>>>(X, w_ih, b_ih, gi,
                                                            ROWS, G3, HID, 0);
    for (int t = 0; t < T_STEPS; ++t) {
        float* cur  = (t & 1) ? hT1 : hT0;
        float* next = (t & 1) ? hT0 : hT1;
        gru_step<<<256, 256, 0, stream>>>(cur, next, w_hh, b_hh,
                                          gi + (size_t)t * BATCH * G3,
                                          Hall + (size_t)t * BATCH * HID,
                                          (t == T_STEPS - 1) ? (out + OUT_HID_OFF) : nullptr);
    }
    gemm_bias<<<dim3(VOCABN / BN, ROWS / BM), 256, 0, stream>>>(Hall, out_w, out_b, out,
                                                                ROWS, VOCABN, HID, 1);
    log_softmax_rows<<<ROWS, 256, 0, stream>>>(out);
}

// Round 2
// 1819.084 us; speedup vs baseline: 1.8057x; 1.8057x over previous
//
#include <hip/hip_runtime.h>
#include <math.h>

#define T_STEPS 30
#define BATCH   64
#define HID     1024
#define VOCABN  32000
#define G3      3072
#define ROWS    (T_STEPS * BATCH)   // 1920
#define OUT_HID_OFF ((size_t)BATCH * T_STEPS * VOCABN)  // 61,440,000

typedef __attribute__((ext_vector_type(8))) short bf16x8;
typedef __attribute__((ext_vector_type(4))) float f32x4;

__device__ __forceinline__ unsigned short f2bf(float f) {
    union { float f; unsigned u; } x; x.f = f;
    unsigned r = x.u + 0x7fffu + ((x.u >> 16) & 1u);
    return (unsigned short)(r >> 16);
}

// ---------------------------------------------------------------- K0: h0 -> hT[k][b] (fp32)
__global__ __launch_bounds__(256) void transpose_h0(const float* __restrict__ h0,
                                                    float* __restrict__ hT) {
    int idx = blockIdx.x * 256 + threadIdx.x;   // 0..65535
    int k = idx >> 6, b = idx & 63;
    hT[idx] = h0[b * HID + k];
}

// ---------------------------------------------------------------- K1: fp32 -> bf16 (RNE)
__global__ __launch_bounds__(256) void f32_to_bf16(const float* __restrict__ src,
                                                   unsigned short* __restrict__ dst, int n4) {
    int i = blockIdx.x * 256 + threadIdx.x;
    int stride = gridDim.x * 256;
    for (; i < n4; i += stride) {
        float4 v = ((const float4*)src)[i];
        ushort4 o;
        o.x = f2bf(v.x); o.y = f2bf(v.y); o.z = f2bf(v.z); o.w = f2bf(v.w);
        ((ushort4*)dst)[i] = o;
    }
}

// ---------------------------------------------------------------- K2: X = relu(emb[tok]) -> bf16
__global__ __launch_bounds__(256) void embed_relu_bf16(const int* __restrict__ target,
                                                       const float* __restrict__ emb,
                                                       unsigned short* __restrict__ X) {
    int bid = blockIdx.x;           // t*64 + b
    int t = bid >> 6, b = bid & 63;
    int tok = (t == 0) ? 0 : target[b * T_STEPS + (t - 1)];
    const float4* src = (const float4*)(emb + (size_t)tok * HID);
    float4 v = src[threadIdx.x];
    ushort4 o;
    o.x = f2bf(fmaxf(v.x, 0.f)); o.y = f2bf(fmaxf(v.y, 0.f));
    o.z = f2bf(fmaxf(v.z, 0.f)); o.w = f2bf(fmaxf(v.w, 0.f));
    ((ushort4*)(X + (size_t)bid * HID))[threadIdx.x] = o;
}

// ---------------------------------------------------------------- K3/K5: bf16 MFMA GEMM, C = A@W^T + bias
// A [M][K], W [N][K] bf16 row-major, K % 64 == 0, M % 128 == 0, N % 128 == 0.
// mode 0: out[gr][gc] fp32 row-major. mode 1: gr=t*64+b -> out[(b*30+t)*N + gc].
__global__ __launch_bounds__(256) void gemm_mfma_bt(const unsigned short* __restrict__ A,
                                                    const unsigned short* __restrict__ W,
                                                    const float* __restrict__ bias,
                                                    float* __restrict__ out,
                                                    int N, int K, int mode) {
    __shared__ unsigned short As[128 * 64];   // 16 KB, row = 64 bf16 = 128 B
    __shared__ unsigned short Bs[128 * 64];   // 16 KB
    int tid  = threadIdx.x;
    int lane = tid & 63;
    int wid  = tid >> 6;
    int wm   = wid >> 1, wn = wid & 1;
    const int bM = blockIdx.y * 128;
    const int bN = blockIdx.x * 128;

    f32x4 acc[4][4];
#pragma unroll
    for (int i = 0; i < 4; ++i)
#pragma unroll
        for (int j = 0; j < 4; ++j) acc[i][j] = (f32x4){0.f, 0.f, 0.f, 0.f};

    // staging geometry: wave wid, call q -> LDS bytes [(wid*4+q)*1024, +1024), lane writes +lane*16.
    // LDS row r = (wid*4+q)*8 + (lane>>3) (128 B rows), physical 16B-chunk c = lane&7.
    // source global 16B-chunk = c ^ (r&7)  (inverse of read-side XOR swizzle)
    int sr[4], sc[4];
#pragma unroll
    for (int q = 0; q < 4; ++q) {
        sr[q] = (wid * 4 + q) * 8 + (lane >> 3);
        sc[q] = (lane & 7) ^ (sr[q] & 7);
    }

    for (int kt = 0; kt < K; kt += 64) {
        __syncthreads();   // previous compute done before overwrite
#pragma unroll
        for (int q = 0; q < 4; ++q) {
            const unsigned short* ga = A + (size_t)(bM + sr[q]) * K + kt + sc[q] * 8;
            const unsigned short* gb = W + (size_t)(bN + sr[q]) * K + kt + sc[q] * 8;
            __builtin_amdgcn_global_load_lds(
                (const __attribute__((address_space(1))) unsigned*)ga,
                (__attribute__((address_space(3))) unsigned*)(As + (wid * 4 + q) * 512),
                16, 0, 0);
            __builtin_amdgcn_global_load_lds(
                (const __attribute__((address_space(1))) unsigned*)gb,
                (__attribute__((address_space(3))) unsigned*)(Bs + (wid * 4 + q) * 512),
                16, 0, 0);
        }
        __syncthreads();   // compiler emits vmcnt(0) drain here

#pragma unroll
        for (int ks = 0; ks < 2; ++ks) {
            bf16x8 a[4], b[4];
#pragma unroll
            for (int mf = 0; mf < 4; ++mf) {
                int r  = wm * 64 + mf * 16 + (lane & 15);
                int ch = (ks * 4 + (lane >> 4)) ^ (r & 7);
                a[mf] = *(const bf16x8*)(As + r * 64 + ch * 8);
            }
#pragma unroll
            for (int nf = 0; nf < 4; ++nf) {
                int r  = wn * 64 + nf * 16 + (lane & 15);
                int ch = (ks * 4 + (lane >> 4)) ^ (r & 7);
                b[nf] = *(const bf16x8*)(Bs + r * 64 + ch * 8);
            }
#pragma unroll
            for (int mf = 0; mf < 4; ++mf)
#pragma unroll
                for (int nf = 0; nf < 4; ++nf)
                    acc[mf][nf] = __builtin_amdgcn_mfma_f32_16x16x32_bf16(
                        a[mf], b[nf], acc[mf][nf], 0, 0, 0);
        }
    }

    // epilogue: C/D layout col = lane&15, row = (lane>>4)*4 + j  (m89-verified)
    int rif = (lane >> 4) * 4;
    int col = lane & 15;
#pragma unroll
    for (int mf = 0; mf < 4; ++mf) {
#pragma unroll
        for (int j = 0; j < 4; ++j) {
            int gr = bM + wm * 64 + mf * 16 + rif + j;
            size_t rowoff;
            if (mode == 1) {
                int t = gr >> 6, b = gr & 63;
                rowoff = ((size_t)b * T_STEPS + t) * (size_t)N;
            } else {
                rowoff = (size_t)gr * (size_t)N;
            }
#pragma unroll
            for (int nf = 0; nf < 4; ++nf) {
                int gc = bN + wn * 64 + nf * 16 + col;
                out[rowoff + gc] = acc[mf][nf][j] + bias[gc];
            }
        }
    }
}

// ---------------------------------------------------------------- K4: one GRU step (fp32 recurrence)
__global__ __launch_bounds__(256) void gru_step(const float* __restrict__ hT_cur,
                                                float* __restrict__ hT_next,
                                                const float* __restrict__ w_hh,
                                                const float* __restrict__ b_hh,
                                                const float* __restrict__ gi_t,
                                                unsigned short* __restrict__ H_all_t,
                                                float* __restrict__ h_final_out) {
    __shared__ float sh[128 * 64];   // 32 KB chunk of hT
    int tid = threadIdx.x;
    int lane = tid & 63;
    int w = tid >> 6;
    int m = __builtin_amdgcn_readfirstlane(blockIdx.x * 4 + w);
    const float* wr_p = w_hh + (size_t)m * HID;
    const float* wz_p = w_hh + (size_t)(HID + m) * HID;
    const float* wn_p = w_hh + (size_t)(2 * HID + m) * HID;
    float accr = 0.f, accz = 0.f, accn = 0.f;

    for (int c = 0; c < 8; ++c) {
        __syncthreads();
        const float4* src = (const float4*)(hT_cur + c * 8192);
        float4* dst = (float4*)sh;
#pragma unroll
        for (int q = 0; q < 8; ++q) dst[q * 256 + tid] = src[q * 256 + tid];
        __syncthreads();
        int kbase = c * 128;
#pragma unroll 4
        for (int k = 0; k < 128; ++k) {
            float hv = sh[k * 64 + lane];
            accr += hv * wr_p[kbase + k];
            accz += hv * wz_p[kbase + k];
            accn += hv * wn_p[kbase + k];
        }
    }

    int b = lane;
    const float* gi = gi_t + (size_t)b * G3;
    float ir = gi[m], iz = gi[HID + m], in_ = gi[2 * HID + m];
    float hr = accr + b_hh[m];
    float hz = accz + b_hh[HID + m];
    float hn = accn + b_hh[2 * HID + m];
    float r = 1.0f / (1.0f + expf(-(ir + hr)));
    float z = 1.0f / (1.0f + expf(-(iz + hz)));
    float n = tanhf(in_ + r * hn);
    float hp = hT_cur[(size_t)m * 64 + lane];
    float hnew = (1.0f - z) * n + z * hp;
    hT_next[(size_t)m * 64 + lane] = hnew;
    H_all_t[(size_t)b * HID + m] = f2bf(hnew);
    if (h_final_out) h_final_out[(size_t)b * HID + m] = hnew;
}

// ---------------------------------------------------------------- K6: in-place log_softmax per row
__global__ __launch_bounds__(256) void log_softmax_rows(float* __restrict__ out) {
    float* p = out + (size_t)blockIdx.x * VOCABN;
    int tid = threadIdx.x;
    int lane = tid & 63, w = tid >> 6;
    __shared__ float redm[4], reds[4], bcast[2];

    float m = -1e30f;
    for (int i = tid; i < VOCABN; i += 256) m = fmaxf(m, p[i]);
#pragma unroll
    for (int off = 32; off > 0; off >>= 1) m = fmaxf(m, __shfl_down(m, off, 64));
    if (lane == 0) redm[w] = m;
    __syncthreads();
    if (tid == 0) bcast[0] = fmaxf(fmaxf(redm[0], redm[1]), fmaxf(redm[2], redm[3]));
    __syncthreads();
    float mx = bcast[0];

    float s = 0.f;
    for (int i = tid; i < VOCABN; i += 256) s += expf(p[i] - mx);
#pragma unroll
    for (int off = 32; off > 0; off >>= 1) s += __shfl_down(s, off, 64);
    if (lane == 0) reds[w] = s;
    __syncthreads();
    if (tid == 0) bcast[1] = logf(reds[0] + reds[1] + reds[2] + reds[3]);
    __syncthreads();
    float lg = bcast[1];

    for (int i = tid; i < VOCABN; i += 256) p[i] = p[i] - mx - lg;
}

// ----------------------------------------------------------------
extern "C" void kernel_launch(void* const* d_in, const int* in_sizes, int n_in,
                              void* d_out, int out_size, void* d_ws, size_t ws_size,
                              hipStream_t stream) {
    const float* enc_h  = (const float*)d_in[1];
    const int*   target = (const int*)d_in[2];
    const float* emb    = (const float*)d_in[3];
    const float* w_ih   = (const float*)d_in[4];
    const float* w_hh   = (const float*)d_in[5];
    const float* b_ih   = (const float*)d_in[6];
    const float* b_hh   = (const float*)d_in[7];
    const float* out_w  = (const float*)d_in[8];
    const float* out_b  = (const float*)d_in[9];
    float* out = (float*)d_out;

    // workspace carve (bytes): ~104 MB total
    char* p = (char*)d_ws;
    unsigned short* Xb   = (unsigned short*)p; p += (size_t)ROWS * HID * 2;    // 3.93 MB
    unsigned short* Wih  = (unsigned short*)p; p += (size_t)G3 * HID * 2;      // 6.29 MB
    unsigned short* OutW = (unsigned short*)p; p += (size_t)VOCABN * HID * 2;  // 65.5 MB
    unsigned short* Hall = (unsigned short*)p; p += (size_t)ROWS * HID * 2;    // 3.93 MB
    float* gi  = (float*)p; p += (size_t)ROWS * G3 * 4;                        // 23.6 MB
    float* hT0 = (float*)p; p += (size_t)HID * BATCH * 4;
    float* hT1 = (float*)p; p += (size_t)HID * BATCH * 4;

    transpose_h0<<<256, 256, 0, stream>>>(enc_h, hT0);
    f32_to_bf16<<<768, 256, 0, stream>>>(w_ih, Wih, G3 * HID / 4);
    f32_to_bf16<<<2048, 256, 0, stream>>>(out_w, OutW, VOCABN * HID / 4);
    embed_relu_bf16<<<ROWS, 256, 0, stream>>>(target, emb, Xb);

    gemm_mfma_bt<<<dim3(G3 / 128, ROWS / 128), 256, 0, stream>>>(
        Xb, Wih, b_ih, gi, G3, HID, 0);

    for (int t = 0; t < T_STEPS; ++t) {
        float* cur  = (t & 1) ? hT1 : hT0;
        float* next = (t & 1) ? hT0 : hT1;
        gru_step<<<256, 256, 0, stream>>>(cur, next, w_hh, b_hh,
                                          gi + (size_t)t * BATCH * G3,
                                          Hall + (size_t)t * BATCH * HID,
                                          (t == T_STEPS - 1) ? (out + OUT_HID_OFF) : nullptr);
    }

    gemm_mfma_bt<<<dim3(VOCABN / 128, ROWS / 128), 256, 0, stream>>>(
        Hall, OutW, out_b, out, VOCABN, HID, 1);

    log_softmax_rows<<<ROWS, 256, 0, stream>>>(out);
}

// Round 3
// 920.518 us; speedup vs baseline: 3.5684x; 1.9762x over previous
//
#include <hip/hip_runtime.h>
#include <math.h>

#define T_STEPS 30
#define BATCH   64
#define HID     1024
#define VOCABN  32000
#define G3      3072
#define ROWS    (T_STEPS * BATCH)   // 1920
#define OUT_HID_OFF ((size_t)BATCH * T_STEPS * VOCABN)  // 61,440,000
#define NBY 15                      // logits GEMM M-blocks
#define NBX 250                     // logits GEMM N-blocks
#define NPART 500                   // softmax partials per row (NBX * 2 waves)

typedef __attribute__((ext_vector_type(8))) short bf16x8;
typedef __attribute__((ext_vector_type(4))) float f32x4;

__device__ __forceinline__ unsigned short f2bf(float f) {
    union { float f; unsigned u; } x; x.f = f;
    unsigned r = x.u + 0x7fffu + ((x.u >> 16) & 1u);
    return (unsigned short)(r >> 16);
}

__device__ __forceinline__ void gld_lds16(const unsigned short* g, unsigned short* l) {
    __builtin_amdgcn_global_load_lds(
        (const __attribute__((address_space(1))) unsigned*)g,
        (__attribute__((address_space(3))) unsigned*)l, 16, 0, 0);
}

// ---------------------------------------------------------------- fp32 -> bf16 (RNE)
__global__ __launch_bounds__(256) void f32_to_bf16(const float* __restrict__ src,
                                                   unsigned short* __restrict__ dst, int n4) {
    int i = blockIdx.x * 256 + threadIdx.x;
    int stride = gridDim.x * 256;
    for (; i < n4; i += stride) {
        float4 v = ((const float4*)src)[i];
        ushort4 o;
        o.x = f2bf(v.x); o.y = f2bf(v.y); o.z = f2bf(v.z); o.w = f2bf(v.w);
        ((ushort4*)dst)[i] = o;
    }
}

// ---------------------------------------------------------------- X = relu(emb[tok]) -> bf16
__global__ __launch_bounds__(256) void embed_relu_bf16(const int* __restrict__ target,
                                                       const float* __restrict__ emb,
                                                       unsigned short* __restrict__ X) {
    int bid = blockIdx.x;           // t*64 + b
    int t = bid >> 6, b = bid & 63;
    int tok = (t == 0) ? 0 : target[b * T_STEPS + (t - 1)];
    const float4* src = (const float4*)(emb + (size_t)tok * HID);
    float4 v = src[threadIdx.x];
    ushort4 o;
    o.x = f2bf(fmaxf(v.x, 0.f)); o.y = f2bf(fmaxf(v.y, 0.f));
    o.z = f2bf(fmaxf(v.z, 0.f)); o.w = f2bf(fmaxf(v.w, 0.f));
    ((ushort4*)(X + (size_t)bid * HID))[threadIdx.x] = o;
}

// ---------------------------------------------------------------- gi GEMM (mode 0 of round 2)
__global__ __launch_bounds__(256) void gemm_mfma_bt(const unsigned short* __restrict__ A,
                                                    const unsigned short* __restrict__ W,
                                                    const float* __restrict__ bias,
                                                    float* __restrict__ out,
                                                    int N, int K) {
    __shared__ unsigned short As[128 * 64];
    __shared__ unsigned short Bs[128 * 64];
    int tid  = threadIdx.x;
    int lane = tid & 63;
    int wid  = tid >> 6;
    int wm   = wid >> 1, wn = wid & 1;
    const int bM = blockIdx.y * 128;
    const int bN = blockIdx.x * 128;

    f32x4 acc[4][4];
#pragma unroll
    for (int i = 0; i < 4; ++i)
#pragma unroll
        for (int j = 0; j < 4; ++j) acc[i][j] = (f32x4){0.f, 0.f, 0.f, 0.f};

    int sr[4], sc[4];
#pragma unroll
    for (int q = 0; q < 4; ++q) {
        sr[q] = (wid * 4 + q) * 8 + (lane >> 3);
        sc[q] = (lane & 7) ^ (sr[q] & 7);
    }

    for (int kt = 0; kt < K; kt += 64) {
        __syncthreads();
#pragma unroll
        for (int q = 0; q < 4; ++q) {
            gld_lds16(A + (size_t)(bM + sr[q]) * K + kt + sc[q] * 8, As + (wid * 4 + q) * 512);
            gld_lds16(W + (size_t)(bN + sr[q]) * K + kt + sc[q] * 8, Bs + (wid * 4 + q) * 512);
        }
        __syncthreads();

#pragma unroll
        for (int ks = 0; ks < 2; ++ks) {
            bf16x8 a[4], b[4];
#pragma unroll
            for (int mf = 0; mf < 4; ++mf) {
                int r  = wm * 64 + mf * 16 + (lane & 15);
                int ch = (ks * 4 + (lane >> 4)) ^ (r & 7);
                a[mf] = *(const bf16x8*)(As + r * 64 + ch * 8);
            }
#pragma unroll
            for (int nf = 0; nf < 4; ++nf) {
                int r  = wn * 64 + nf * 16 + (lane & 15);
                int ch = (ks * 4 + (lane >> 4)) ^ (r & 7);
                b[nf] = *(const bf16x8*)(Bs + r * 64 + ch * 8);
            }
#pragma unroll
            for (int mf = 0; mf < 4; ++mf)
#pragma unroll
                for (int nf = 0; nf < 4; ++nf)
                    acc[mf][nf] = __builtin_amdgcn_mfma_f32_16x16x32_bf16(
                        a[mf], b[nf], acc[mf][nf], 0, 0, 0);
        }
    }

    int rif = (lane >> 4) * 4;
    int col = lane & 15;
#pragma unroll
    for (int mf = 0; mf < 4; ++mf) {
#pragma unroll
        for (int j = 0; j < 4; ++j) {
            int gr = bM + wm * 64 + mf * 16 + rif + j;
#pragma unroll
            for (int nf = 0; nf < 4; ++nf) {
                int gc = bN + wn * 64 + nf * 16 + col;
                out[(size_t)gr * N + gc] = acc[mf][nf][j] + bias[gc];
            }
        }
    }
}

// ---------------------------------------------------------------- logits GEMM + row permute + softmax partials
__global__ __launch_bounds__(256) void gemm_logits(const unsigned short* __restrict__ A,
                                                   const unsigned short* __restrict__ W,
                                                   const float* __restrict__ bias,
                                                   float* __restrict__ out,
                                                   float2* __restrict__ pstat) {
    __shared__ unsigned short As[128 * 64];
    __shared__ unsigned short Bs[128 * 64];
    // bijective XCD remap of 3750 blocks (3750 = 8*468 + 6)
    int orig = blockIdx.x;
    int xcd = orig & 7, idx = orig >> 3;
    int wg = (xcd < 6) ? xcd * 469 + idx : 6 * 469 + (xcd - 6) * 468 + idx;
    int bx = wg / NBY;          // OutW panel: consecutive wg share bx -> L2 reuse
    int by = wg - bx * NBY;
    const int bM = by * 128;
    const int bN = bx * 128;
    const int K = HID;

    int tid  = threadIdx.x;
    int lane = tid & 63;
    int wid  = tid >> 6;
    int wm   = wid >> 1, wn = wid & 1;

    f32x4 acc[4][4];
#pragma unroll
    for (int i = 0; i < 4; ++i)
#pragma unroll
        for (int j = 0; j < 4; ++j) acc[i][j] = (f32x4){0.f, 0.f, 0.f, 0.f};

    int sr[4], sc[4];
#pragma unroll
    for (int q = 0; q < 4; ++q) {
        sr[q] = (wid * 4 + q) * 8 + (lane >> 3);
        sc[q] = (lane & 7) ^ (sr[q] & 7);
    }

    for (int kt = 0; kt < K; kt += 64) {
        __syncthreads();
#pragma unroll
        for (int q = 0; q < 4; ++q) {
            gld_lds16(A + (size_t)(bM + sr[q]) * K + kt + sc[q] * 8, As + (wid * 4 + q) * 512);
            gld_lds16(W + (size_t)(bN + sr[q]) * K + kt + sc[q] * 8, Bs + (wid * 4 + q) * 512);
        }
        __syncthreads();

#pragma unroll
        for (int ks = 0; ks < 2; ++ks) {
            bf16x8 a[4], b[4];
#pragma unroll
            for (int mf = 0; mf < 4; ++mf) {
                int r  = wm * 64 + mf * 16 + (lane & 15);
                int ch = (ks * 4 + (lane >> 4)) ^ (r & 7);
                a[mf] = *(const bf16x8*)(As + r * 64 + ch * 8);
            }
#pragma unroll
            for (int nf = 0; nf < 4; ++nf) {
                int r  = wn * 64 + nf * 16 + (lane & 15);
                int ch = (ks * 4 + (lane >> 4)) ^ (r & 7);
                b[nf] = *(const bf16x8*)(Bs + r * 64 + ch * 8);
            }
#pragma unroll
            for (int mf = 0; mf < 4; ++mf)
#pragma unroll
                for (int nf = 0; nf < 4; ++nf)
                    acc[mf][nf] = __builtin_amdgcn_mfma_f32_16x16x32_bf16(
                        a[mf], b[nf], acc[mf][nf], 0, 0, 0);
        }
    }

    int rif = (lane >> 4) * 4;
    int col = lane & 15;
#pragma unroll
    for (int mf = 0; mf < 4; ++mf) {
#pragma unroll
        for (int j = 0; j < 4; ++j) {
            int gr = bM + wm * 64 + mf * 16 + rif + j;
            int t = gr >> 6, b = gr & 63;
            int prow = b * T_STEPS + t;
            float v[4];
            float mx = -1e30f;
#pragma unroll
            for (int nf = 0; nf < 4; ++nf) {
                int gc = bN + wn * 64 + nf * 16 + col;
                v[nf] = acc[mf][nf][j] + bias[gc];
                out[(size_t)prow * VOCABN + gc] = v[nf];
                mx = fmaxf(mx, v[nf]);
            }
#pragma unroll
            for (int off = 1; off < 16; off <<= 1) mx = fmaxf(mx, __shfl_xor(mx, off, 64));
            float se = 0.f;
#pragma unroll
            for (int nf = 0; nf < 4; ++nf) se += __expf(v[nf] - mx);
#pragma unroll
            for (int off = 1; off < 16; off <<= 1) se += __shfl_xor(se, off, 64);
            if (col == 0) pstat[(size_t)prow * NPART + bx * 2 + wn] = make_float2(mx, se);
        }
    }
}

// ---------------------------------------------------------------- one GRU step: MFMA gh + fused gates
// 32 blocks, block n0 owns m in [n0*32, n0*32+32). 4 waves: (wid>>1)=batch half, (wid&1)=m 16-group.
__global__ __launch_bounds__(256) void gru_step_mfma(
    const unsigned short* __restrict__ Abf,   // h_prev bf16 [64][1024]
    const float* __restrict__ hprev,          // h_prev fp32 [64][1024]
    const unsigned short* __restrict__ Whh,   // bf16 [3072][1024]
    const float* __restrict__ b_hh,
    const float* __restrict__ gi_t,           // [64][3072] fp32
    unsigned short* __restrict__ hout_bf,     // [64][1024]
    float* __restrict__ hout_f32,             // [64][1024]
    float* __restrict__ h_final)              // fp32 [64][1024] or null
{
    __shared__ unsigned short As[2][64 * 64];   // 8 KB per buf
    __shared__ unsigned short Ws[2][96 * 64];   // 12 KB per buf
    int tid  = threadIdx.x;
    int lane = tid & 63;
    int wid  = tid >> 6;
    int l15  = lane & 15, l4 = lane >> 4;
    int half = wid >> 1;
    int mq   = wid & 1;
    int n0   = blockIdx.x;

    f32x4 acc[2][3];
#pragma unroll
    for (int i = 0; i < 2; ++i)
#pragma unroll
        for (int g = 0; g < 3; ++g) acc[i][g] = (f32x4){0.f, 0.f, 0.f, 0.f};

    auto stage = [&](int buf, int kt) {
#pragma unroll
        for (int q = 0; q < 2; ++q) {
            int c = (wid * 2 + q) * 64 + lane;
            int r = c >> 3, cc = c & 7;
            gld_lds16(Abf + (size_t)r * HID + kt * 64 + ((cc ^ (r & 7)) << 3),
                      &As[buf][(wid * 2 + q) * 512]);
        }
#pragma unroll
        for (int q = 0; q < 3; ++q) {
            int c = (wid * 3 + q) * 64 + lane;
            int r = c >> 3, cc = c & 7;
            int grow = (r >> 5) * HID + n0 * 32 + (r & 31);
            gld_lds16(Whh + (size_t)grow * HID + kt * 64 + ((cc ^ (r & 7)) << 3),
                      &Ws[buf][(wid * 3 + q) * 512]);
        }
    };

    stage(0, 0);
    __syncthreads();
    for (int kt = 0; kt < 16; ++kt) {
        int cur = kt & 1;
        if (kt < 15) stage(cur ^ 1, kt + 1);
#pragma unroll
        for (int ks = 0; ks < 2; ++ks) {
            bf16x8 a[2], b[3];
#pragma unroll
            for (int mf = 0; mf < 2; ++mf) {
                int r  = half * 32 + mf * 16 + l15;
                int ch = (ks * 4 + l4) ^ (r & 7);
                a[mf] = *(const bf16x8*)&As[cur][r * 64 + ch * 8];
            }
#pragma unroll
            for (int g = 0; g < 3; ++g) {
                int r  = g * 32 + mq * 16 + l15;
                int ch = (ks * 4 + l4) ^ (r & 7);
                b[g] = *(const bf16x8*)&Ws[cur][r * 64 + ch * 8];
            }
#pragma unroll
            for (int mf = 0; mf < 2; ++mf)
#pragma unroll
                for (int g = 0; g < 3; ++g)
                    acc[mf][g] = __builtin_amdgcn_mfma_f32_16x16x32_bf16(
                        a[mf], b[g], acc[mf][g], 0, 0, 0);
        }
        __syncthreads();
    }

    int rif = l4 * 4;
    int m_g = n0 * 32 + mq * 16 + l15;
    float bhr = b_hh[m_g], bhz = b_hh[HID + m_g], bhn = b_hh[2 * HID + m_g];
#pragma unroll
    for (int mf = 0; mf < 2; ++mf) {
#pragma unroll
        for (int j = 0; j < 4; ++j) {
            int b = half * 32 + mf * 16 + rif + j;
            const float* gib = gi_t + (size_t)b * G3;
            float ir = gib[m_g], iz = gib[HID + m_g], in_ = gib[2 * HID + m_g];
            float hr = acc[mf][0][j] + bhr;
            float hz = acc[mf][1][j] + bhz;
            float hn = acc[mf][2][j] + bhn;
            float r = 1.f / (1.f + __expf(-(ir + hr)));
            float z = 1.f / (1.f + __expf(-(iz + hz)));
            float n = tanhf(in_ + r * hn);
            float hp = hprev[(size_t)b * HID + m_g];
            float hnew = (1.f - z) * n + z * hp;
            hout_f32[(size_t)b * HID + m_g] = hnew;
            hout_bf[(size_t)b * HID + m_g] = f2bf(hnew);
            if (h_final) h_final[(size_t)b * HID + m_g] = hnew;
        }
    }
}

// ---------------------------------------------------------------- softmax partial reduce (1 wave/row)
__global__ __launch_bounds__(64) void lsm_reduce(const float2* __restrict__ pstat,
                                                 float2* __restrict__ stats) {
    int lane = threadIdx.x;
    const float2* p = pstat + (size_t)blockIdx.x * NPART;
    float m = -1e30f;
    for (int i = lane; i < NPART; i += 64) m = fmaxf(m, p[i].x);
#pragma unroll
    for (int off = 1; off < 64; off <<= 1) m = fmaxf(m, __shfl_xor(m, off, 64));
    float s = 0.f;
    for (int i = lane; i < NPART; i += 64) { float2 t = p[i]; s += t.y * __expf(t.x - m); }
#pragma unroll
    for (int off = 1; off < 64; off <<= 1) s += __shfl_xor(s, off, 64);
    if (lane == 0) stats[blockIdx.x] = make_float2(m, logf(s));
}

// ---------------------------------------------------------------- apply: out -= mx + logZ
__global__ __launch_bounds__(256) void lsm_apply(float* __restrict__ out,
                                                 const float2* __restrict__ stats) {
    int i = blockIdx.x * 256 + threadIdx.x;
    int stride = gridDim.x * 256;
    const int total4 = ROWS * VOCABN / 4;   // 15,360,000
    for (; i < total4; i += stride) {
        int row = i / (VOCABN / 4);
        float2 st = stats[row];
        float c = st.x + st.y;
        float4 v = ((float4*)out)[i];
        v.x -= c; v.y -= c; v.z -= c; v.w -= c;
        ((float4*)out)[i] = v;
    }
}

// ----------------------------------------------------------------
extern "C" void kernel_launch(void* const* d_in, const int* in_sizes, int n_in,
                              void* d_out, int out_size, void* d_ws, size_t ws_size,
                              hipStream_t stream) {
    const float* enc_h  = (const float*)d_in[1];
    const int*   target = (const int*)d_in[2];
    const float* emb    = (const float*)d_in[3];
    const float* w_ih   = (const float*)d_in[4];
    const float* w_hh   = (const float*)d_in[5];
    const float* b_ih   = (const float*)d_in[6];
    const float* b_hh   = (const float*)d_in[7];
    const float* out_w  = (const float*)d_in[8];
    const float* out_b  = (const float*)d_in[9];
    float* out = (float*)d_out;

    char* p = (char*)d_ws;
    unsigned short* Xb   = (unsigned short*)p; p += (size_t)ROWS * HID * 2;    // dead after gi GEMM
    unsigned short* Wih  = (unsigned short*)p; p += (size_t)G3 * HID * 2;      // dead after gi GEMM
    unsigned short* OutW = (unsigned short*)p; p += (size_t)VOCABN * HID * 2;
    unsigned short* Hall = (unsigned short*)p; p += (size_t)ROWS * HID * 2;
    float* gi   = (float*)p; p += (size_t)ROWS * G3 * 4;
    unsigned short* Whhb = (unsigned short*)p; p += (size_t)G3 * HID * 2;
    unsigned short* h0b  = (unsigned short*)p; p += (size_t)BATCH * HID * 2;
    float* hF0  = (float*)p; p += (size_t)BATCH * HID * 4;
    float* hF1  = (float*)p; p += (size_t)BATCH * HID * 4;
    float2* stats = (float2*)p; p += (size_t)ROWS * 8;
    float2* pstat = (float2*)Xb;   // 7.68 MB, overlays Xb+Wih (dead by then)

    f32_to_bf16<<<768, 256, 0, stream>>>(w_ih, Wih, G3 * HID / 4);
    f32_to_bf16<<<768, 256, 0, stream>>>(w_hh, Whhb, G3 * HID / 4);
    f32_to_bf16<<<2048, 256, 0, stream>>>(out_w, OutW, VOCABN * HID / 4);
    f32_to_bf16<<<64, 256, 0, stream>>>(enc_h, h0b, BATCH * HID / 4);
    embed_relu_bf16<<<ROWS, 256, 0, stream>>>(target, emb, Xb);

    gemm_mfma_bt<<<dim3(G3 / 128, ROWS / 128), 256, 0, stream>>>(Xb, Wih, b_ih, gi, G3, HID);

    for (int t = 0; t < T_STEPS; ++t) {
        const unsigned short* Abf = (t == 0) ? h0b : (Hall + (size_t)(t - 1) * BATCH * HID);
        const float* hpf = (t == 0) ? enc_h : (((t - 1) & 1) ? hF1 : hF0);
        float* hof = (t & 1) ? hF1 : hF0;
        gru_step_mfma<<<32, 256, 0, stream>>>(
            Abf, hpf, Whhb, b_hh, gi + (size_t)t * BATCH * G3,
            Hall + (size_t)t * BATCH * HID, hof,
            (t == T_STEPS - 1) ? (out + OUT_HID_OFF) : nullptr);
    }

    gemm_logits<<<NBX * NBY, 256, 0, stream>>>(Hall, OutW, out_b, out, pstat);
    lsm_reduce<<<ROWS, 64, 0, stream>>>(pstat, stats);
    lsm_apply<<<2048, 256, 0, stream>>>(out, stats);
}

// Round 4
// 917.576 us; speedup vs baseline: 3.5799x; 1.0032x over previous
//
#include <hip/hip_runtime.h>
#include <hip/hip_cooperative_groups.h>
#include <math.h>

namespace cg = cooperative_groups;

#define T_STEPS 30
#define BATCH   64
#define HID     1024
#define VOCABN  32000
#define G3      3072
#define ROWS    (T_STEPS * BATCH)   // 1920
#define OUT_HID_OFF ((size_t)BATCH * T_STEPS * VOCABN)  // 61,440,000
#define NBY 15
#define NBX 250
#define NPART 500

typedef __attribute__((ext_vector_type(8))) short bf16x8;
typedef __attribute__((ext_vector_type(4))) float f32x4;

__device__ __forceinline__ unsigned short f2bf(float f) {
    union { float f; unsigned u; } x; x.f = f;
    unsigned r = x.u + 0x7fffu + ((x.u >> 16) & 1u);
    return (unsigned short)(r >> 16);
}

__device__ __forceinline__ void gld_lds16(const unsigned short* g, unsigned short* l) {
    __builtin_amdgcn_global_load_lds(
        (const __attribute__((address_space(1))) unsigned*)g,
        (__attribute__((address_space(3))) unsigned*)l, 16, 0, 0);
}

// ---------------------------------------------------------------- fp32 -> bf16 (RNE)
__global__ __launch_bounds__(256) void f32_to_bf16(const float* __restrict__ src,
                                                   unsigned short* __restrict__ dst, int n4) {
    int i = blockIdx.x * 256 + threadIdx.x;
    int stride = gridDim.x * 256;
    for (; i < n4; i += stride) {
        float4 v = ((const float4*)src)[i];
        ushort4 o;
        o.x = f2bf(v.x); o.y = f2bf(v.y); o.z = f2bf(v.z); o.w = f2bf(v.w);
        ((ushort4*)dst)[i] = o;
    }
}

// ---------------------------------------------------------------- X = relu(emb[tok]) -> bf16
__global__ __launch_bounds__(256) void embed_relu_bf16(const int* __restrict__ target,
                                                       const float* __restrict__ emb,
                                                       unsigned short* __restrict__ X) {
    int bid = blockIdx.x;           // t*64 + b
    int t = bid >> 6, b = bid & 63;
    int tok = (t == 0) ? 0 : target[b * T_STEPS + (t - 1)];
    const float4* src = (const float4*)(emb + (size_t)tok * HID);
    float4 v = src[threadIdx.x];
    ushort4 o;
    o.x = f2bf(fmaxf(v.x, 0.f)); o.y = f2bf(fmaxf(v.y, 0.f));
    o.z = f2bf(fmaxf(v.z, 0.f)); o.w = f2bf(fmaxf(v.w, 0.f));
    ((ushort4*)(X + (size_t)bid * HID))[threadIdx.x] = o;
}

// ---------------------------------------------------------------- gi GEMM
__global__ __launch_bounds__(256) void gemm_mfma_bt(const unsigned short* __restrict__ A,
                                                    const unsigned short* __restrict__ W,
                                                    const float* __restrict__ bias,
                                                    float* __restrict__ out,
                                                    int N, int K) {
    __shared__ unsigned short As[128 * 64];
    __shared__ unsigned short Bs[128 * 64];
    int tid  = threadIdx.x;
    int lane = tid & 63;
    int wid  = tid >> 6;
    int wm   = wid >> 1, wn = wid & 1;
    const int bM = blockIdx.y * 128;
    const int bN = blockIdx.x * 128;

    f32x4 acc[4][4];
#pragma unroll
    for (int i = 0; i < 4; ++i)
#pragma unroll
        for (int j = 0; j < 4; ++j) acc[i][j] = (f32x4){0.f, 0.f, 0.f, 0.f};

    int sr[4], sc[4];
#pragma unroll
    for (int q = 0; q < 4; ++q) {
        sr[q] = (wid * 4 + q) * 8 + (lane >> 3);
        sc[q] = (lane & 7) ^ (sr[q] & 7);
    }

    for (int kt = 0; kt < K; kt += 64) {
        __syncthreads();
#pragma unroll
        for (int q = 0; q < 4; ++q) {
            gld_lds16(A + (size_t)(bM + sr[q]) * K + kt + sc[q] * 8, As + (wid * 4 + q) * 512);
            gld_lds16(W + (size_t)(bN + sr[q]) * K + kt + sc[q] * 8, Bs + (wid * 4 + q) * 512);
        }
        __syncthreads();

#pragma unroll
        for (int ks = 0; ks < 2; ++ks) {
            bf16x8 a[4], b[4];
#pragma unroll
            for (int mf = 0; mf < 4; ++mf) {
                int r  = wm * 64 + mf * 16 + (lane & 15);
                int ch = (ks * 4 + (lane >> 4)) ^ (r & 7);
                a[mf] = *(const bf16x8*)(As + r * 64 + ch * 8);
            }
#pragma unroll
            for (int nf = 0; nf < 4; ++nf) {
                int r  = wn * 64 + nf * 16 + (lane & 15);
                int ch = (ks * 4 + (lane >> 4)) ^ (r & 7);
                b[nf] = *(const bf16x8*)(Bs + r * 64 + ch * 8);
            }
#pragma unroll
            for (int mf = 0; mf < 4; ++mf)
#pragma unroll
                for (int nf = 0; nf < 4; ++nf)
                    acc[mf][nf] = __builtin_amdgcn_mfma_f32_16x16x32_bf16(
                        a[mf], b[nf], acc[mf][nf], 0, 0, 0);
        }
    }

    int rif = (lane >> 4) * 4;
    int col = lane & 15;
#pragma unroll
    for (int mf = 0; mf < 4; ++mf) {
#pragma unroll
        for (int j = 0; j < 4; ++j) {
            int gr = bM + wm * 64 + mf * 16 + rif + j;
#pragma unroll
            for (int nf = 0; nf < 4; ++nf) {
                int gc = bN + wn * 64 + nf * 16 + col;
                out[(size_t)gr * N + gc] = acc[mf][nf][j] + bias[gc];
            }
        }
    }
}

// ---------------------------------------------------------------- logits GEMM + permute + softmax partials
// round-2 block ordering (2D grid, N fastest), stats epilogue kept
__global__ __launch_bounds__(256) void gemm_logits(const unsigned short* __restrict__ A,
                                                   const unsigned short* __restrict__ W,
                                                   const float* __restrict__ bias,
                                                   float* __restrict__ out,
                                                   float2* __restrict__ pstat) {
    __shared__ unsigned short As[128 * 64];
    __shared__ unsigned short Bs[128 * 64];
    int bx = blockIdx.x;
    int by = blockIdx.y;
    const int bM = by * 128;
    const int bN = bx * 128;
    const int K = HID;

    int tid  = threadIdx.x;
    int lane = tid & 63;
    int wid  = tid >> 6;
    int wm   = wid >> 1, wn = wid & 1;

    f32x4 acc[4][4];
#pragma unroll
    for (int i = 0; i < 4; ++i)
#pragma unroll
        for (int j = 0; j < 4; ++j) acc[i][j] = (f32x4){0.f, 0.f, 0.f, 0.f};

    int sr[4], sc[4];
#pragma unroll
    for (int q = 0; q < 4; ++q) {
        sr[q] = (wid * 4 + q) * 8 + (lane >> 3);
        sc[q] = (lane & 7) ^ (sr[q] & 7);
    }

    for (int kt = 0; kt < K; kt += 64) {
        __syncthreads();
#pragma unroll
        for (int q = 0; q < 4; ++q) {
            gld_lds16(A + (size_t)(bM + sr[q]) * K + kt + sc[q] * 8, As + (wid * 4 + q) * 512);
            gld_lds16(W + (size_t)(bN + sr[q]) * K + kt + sc[q] * 8, Bs + (wid * 4 + q) * 512);
        }
        __syncthreads();

#pragma unroll
        for (int ks = 0; ks < 2; ++ks) {
            bf16x8 a[4], b[4];
#pragma unroll
            for (int mf = 0; mf < 4; ++mf) {
                int r  = wm * 64 + mf * 16 + (lane & 15);
                int ch = (ks * 4 + (lane >> 4)) ^ (r & 7);
                a[mf] = *(const bf16x8*)(As + r * 64 + ch * 8);
            }
#pragma unroll
            for (int nf = 0; nf < 4; ++nf) {
                int r  = wn * 64 + nf * 16 + (lane & 15);
                int ch = (ks * 4 + (lane >> 4)) ^ (r & 7);
                b[nf] = *(const bf16x8*)(Bs + r * 64 + ch * 8);
            }
#pragma unroll
            for (int mf = 0; mf < 4; ++mf)
#pragma unroll
                for (int nf = 0; nf < 4; ++nf)
                    acc[mf][nf] = __builtin_amdgcn_mfma_f32_16x16x32_bf16(
                        a[mf], b[nf], acc[mf][nf], 0, 0, 0);
        }
    }

    int rif = (lane >> 4) * 4;
    int col = lane & 15;
#pragma unroll
    for (int mf = 0; mf < 4; ++mf) {
#pragma unroll
        for (int j = 0; j < 4; ++j) {
            int gr = bM + wm * 64 + mf * 16 + rif + j;
            int t = gr >> 6, b = gr & 63;
            int prow = b * T_STEPS + t;
            float v[4];
            float mx = -1e30f;
#pragma unroll
            for (int nf = 0; nf < 4; ++nf) {
                int gc = bN + wn * 64 + nf * 16 + col;
                v[nf] = acc[mf][nf][j] + bias[gc];
                out[(size_t)prow * VOCABN + gc] = v[nf];
                mx = fmaxf(mx, v[nf]);
            }
#pragma unroll
            for (int off = 1; off < 16; off <<= 1) mx = fmaxf(mx, __shfl_xor(mx, off, 64));
            float se = 0.f;
#pragma unroll
            for (int nf = 0; nf < 4; ++nf) se += __expf(v[nf] - mx);
#pragma unroll
            for (int off = 1; off < 16; off <<= 1) se += __shfl_xor(se, off, 64);
            if (col == 0) pstat[(size_t)prow * NPART + bx * 2 + wn] = make_float2(mx, se);
        }
    }
}

// ---------------------------------------------------------------- persistent 30-step GRU recurrence
// cooperative launch, 64 blocks x 256 threads. Block bid owns m in [bid*16, bid*16+16).
// Wave wid = batch quarter. h_prev fp32 lives in registers (hp[4] per thread).
__global__ __launch_bounds__(256) void gru_persistent(
    const unsigned short* __restrict__ h0b,   // [64][1024] bf16
    const float* __restrict__ enc_h,          // [64][1024] fp32
    const unsigned short* __restrict__ Whh,   // [3072][1024] bf16
    const float* __restrict__ b_hh,
    const float* __restrict__ gi,             // [30][64][3072] fp32
    unsigned short* __restrict__ Hall,        // [30][64][1024] bf16
    float* __restrict__ h_final)              // [64][1024] fp32
{
    __shared__ unsigned short As[2][64 * 128];   // 16 KB x2: A tile, rows=batch, 128 K-cols
    __shared__ unsigned short Ws[2][48 * 128];   // 12 KB x2: W tile, rows=3 gates x 16 m
    cg::grid_group grid = cg::this_grid();

    int tid  = threadIdx.x;
    int lane = tid & 63;
    int wid  = tid >> 6;
    int l15  = lane & 15, l4 = lane >> 4;
    int bid  = blockIdx.x;
    int m0   = bid * 16;
    int m_g  = m0 + l15;
    int bbase = wid * 16 + l4 * 4;

    float hp[4];
#pragma unroll
    for (int j = 0; j < 4; ++j) hp[j] = enc_h[(size_t)(bbase + j) * HID + m_g];
    float bhr = b_hh[m_g], bhz = b_hh[HID + m_g], bhn = b_hh[2 * HID + m_g];

    // staging geometry: 16-chunk (16B) rows of 128 cols; phys chunk cc holds global chunk cc^(r&7)
    int ar[4]; int ac[4];
#pragma unroll
    for (int q = 0; q < 4; ++q) {
        int idx = (wid * 4 + q) * 64 + lane;
        ar[q] = idx >> 4;
        ac[q] = ((idx & 15) ^ (ar[q] & 7)) * 8;
    }
    int wc[3]; size_t wbase[3];
#pragma unroll
    for (int q = 0; q < 3; ++q) {
        int idx = (wid * 3 + q) * 64 + lane;
        int r = idx >> 4;                         // 0..47
        wc[q] = ((idx & 15) ^ (r & 7)) * 8;
        wbase[q] = (size_t)((r >> 4) * HID + m0 + (r & 15)) * HID;
    }

    for (int t = 0; t < T_STEPS; ++t) {
        const unsigned short* Asrc = (t == 0) ? h0b : (Hall + (size_t)(t - 1) * BATCH * HID);

        auto stage = [&](int buf, int kt) {
#pragma unroll
            for (int q = 0; q < 4; ++q)
                gld_lds16(Asrc + (size_t)ar[q] * HID + kt * 128 + ac[q],
                          &As[buf][(wid * 4 + q) * 512]);
#pragma unroll
            for (int q = 0; q < 3; ++q)
                gld_lds16(Whh + wbase[q] + kt * 128 + wc[q],
                          &Ws[buf][(wid * 3 + q) * 512]);
        };

        f32x4 acc[3];
#pragma unroll
        for (int g = 0; g < 3; ++g) acc[g] = (f32x4){0.f, 0.f, 0.f, 0.f};

        stage(0, 0);
        __syncthreads();
        for (int kt = 0; kt < 8; ++kt) {
            int cur = kt & 1;
            if (kt < 7) stage(cur ^ 1, kt + 1);
#pragma unroll
            for (int ks = 0; ks < 4; ++ks) {
                int c = ks * 4 + l4;
                int rA = wid * 16 + l15;
                bf16x8 a = *(const bf16x8*)&As[cur][rA * 128 + ((c ^ (rA & 7)) << 3)];
                bf16x8 b[3];
#pragma unroll
                for (int g = 0; g < 3; ++g) {
                    int rW = g * 16 + l15;
                    b[g] = *(const bf16x8*)&Ws[cur][rW * 128 + ((c ^ (rW & 7)) << 3)];
                }
#pragma unroll
                for (int g = 0; g < 3; ++g)
                    acc[g] = __builtin_amdgcn_mfma_f32_16x16x32_bf16(a, b[g], acc[g], 0, 0, 0);
            }
            __syncthreads();
        }

        const float* git = gi + (size_t)t * BATCH * G3;
        unsigned short* Ht = Hall + (size_t)t * BATCH * HID;
#pragma unroll
        for (int j = 0; j < 4; ++j) {
            int b = bbase + j;
            const float* gib = git + (size_t)b * G3;
            float ir = gib[m_g], iz = gib[HID + m_g], in_ = gib[2 * HID + m_g];
            float r = 1.f / (1.f + __expf(-(ir + acc[0][j] + bhr)));
            float z = 1.f / (1.f + __expf(-(iz + acc[1][j] + bhz)));
            float n = tanhf(in_ + r * (acc[2][j] + bhn));
            float hnew = (1.f - z) * n + z * hp[j];
            hp[j] = hnew;
            Ht[(size_t)b * HID + m_g] = f2bf(hnew);
            if (t == T_STEPS - 1) h_final[(size_t)b * HID + m_g] = hnew;
        }
        grid.sync();
    }
}

// ---------------------------------------------------------------- softmax partial reduce (1 wave/row)
__global__ __launch_bounds__(64) void lsm_reduce(const float2* __restrict__ pstat,
                                                 float2* __restrict__ stats) {
    int lane = threadIdx.x;
    const float2* p = pstat + (size_t)blockIdx.x * NPART;
    float m = -1e30f;
    for (int i = lane; i < NPART; i += 64) m = fmaxf(m, p[i].x);
#pragma unroll
    for (int off = 1; off < 64; off <<= 1) m = fmaxf(m, __shfl_xor(m, off, 64));
    float s = 0.f;
    for (int i = lane; i < NPART; i += 64) { float2 t = p[i]; s += t.y * __expf(t.x - m); }
#pragma unroll
    for (int off = 1; off < 64; off <<= 1) s += __shfl_xor(s, off, 64);
    if (lane == 0) stats[blockIdx.x] = make_float2(m, logf(s));
}

// ---------------------------------------------------------------- apply: out -= mx + logZ
__global__ __launch_bounds__(256) void lsm_apply(float* __restrict__ out,
                                                 const float2* __restrict__ stats) {
    int i = blockIdx.x * 256 + threadIdx.x;
    int stride = gridDim.x * 256;
    const int total4 = ROWS * VOCABN / 4;
    for (; i < total4; i += stride) {
        int row = i / (VOCABN / 4);
        float2 st = stats[row];
        float c = st.x + st.y;
        float4 v = ((float4*)out)[i];
        v.x -= c; v.y -= c; v.z -= c; v.w -= c;
        ((float4*)out)[i] = v;
    }
}

// ----------------------------------------------------------------
extern "C" void kernel_launch(void* const* d_in, const int* in_sizes, int n_in,
                              void* d_out, int out_size, void* d_ws, size_t ws_size,
                              hipStream_t stream) {
    const float* enc_h  = (const float*)d_in[1];
    const int*   target = (const int*)d_in[2];
    const float* emb    = (const float*)d_in[3];
    const float* w_ih   = (const float*)d_in[4];
    const float* w_hh   = (const float*)d_in[5];
    const float* b_ih   = (const float*)d_in[6];
    const float* b_hh   = (const float*)d_in[7];
    const float* out_w  = (const float*)d_in[8];
    const float* out_b  = (const float*)d_in[9];
    float* out = (float*)d_out;

    char* p = (char*)d_ws;
    unsigned short* Xb   = (unsigned short*)p; p += (size_t)ROWS * HID * 2;
    unsigned short* Wih  = (unsigned short*)p; p += (size_t)G3 * HID * 2;
    unsigned short* OutW = (unsigned short*)p; p += (size_t)VOCABN * HID * 2;
    unsigned short* Hall = (unsigned short*)p; p += (size_t)ROWS * HID * 2;
    float* gi   = (float*)p; p += (size_t)ROWS * G3 * 4;
    unsigned short* Whhb = (unsigned short*)p; p += (size_t)G3 * HID * 2;
    unsigned short* h0b  = (unsigned short*)p; p += (size_t)BATCH * HID * 2;
    float2* stats = (float2*)p; p += (size_t)ROWS * 8;
    float2* pstat = (float2*)Xb;   // overlays Xb+Wih (dead after gi GEMM)

    f32_to_bf16<<<768, 256, 0, stream>>>(w_ih, Wih, G3 * HID / 4);
    f32_to_bf16<<<768, 256, 0, stream>>>(w_hh, Whhb, G3 * HID / 4);
    f32_to_bf16<<<2048, 256, 0, stream>>>(out_w, OutW, VOCABN * HID / 4);
    f32_to_bf16<<<64, 256, 0, stream>>>(enc_h, h0b, BATCH * HID / 4);
    embed_relu_bf16<<<ROWS, 256, 0, stream>>>(target, emb, Xb);

    gemm_mfma_bt<<<dim3(G3 / 128, ROWS / 128), 256, 0, stream>>>(Xb, Wih, b_ih, gi, G3, HID);

    {
        const unsigned short* a0 = h0b;
        const float* a1 = enc_h;
        const unsigned short* a2 = Whhb;
        const float* a3 = b_hh;
        const float* a4 = gi;
        unsigned short* a5 = Hall;
        float* a6 = out + OUT_HID_OFF;
        void* args[] = {&a0, &a1, &a2, &a3, &a4, &a5, &a6};
        hipLaunchCooperativeKernel((void*)gru_persistent, dim3(64), dim3(256),
                                   args, 0, stream);
    }

    gemm_logits<<<dim3(NBX, NBY), 256, 0, stream>>>(Hall, OutW, out_b, out, pstat);
    lsm_reduce<<<ROWS, 64, 0, stream>>>(pstat, stats);
    lsm_apply<<<2048, 256, 0, stream>>>(out, stats);
}

// Round 5
// 745.406 us; speedup vs baseline: 4.4067x; 1.2310x over previous
//
#include <hip/hip_runtime.h>
#include <math.h>

#define T_STEPS 30
#define BATCH   64
#define HID     1024
#define VOCABN  32000
#define G3      3072
#define ROWS    (T_STEPS * BATCH)   // 1920
#define OUT_HID_OFF ((size_t)BATCH * T_STEPS * VOCABN)  // 61,440,000
#define NBY 15
#define NBX 250
#define NPART 500

typedef __attribute__((ext_vector_type(8))) short bf16x8;
typedef __attribute__((ext_vector_type(4))) float f32x4;

__device__ __forceinline__ unsigned short f2bf(float f) {
    union { float f; unsigned u; } x; x.f = f;
    unsigned r = x.u + 0x7fffu + ((x.u >> 16) & 1u);
    return (unsigned short)(r >> 16);
}

__device__ __forceinline__ void gld_lds16(const unsigned short* g, unsigned short* l) {
    __builtin_amdgcn_global_load_lds(
        (const __attribute__((address_space(1))) unsigned*)g,
        (__attribute__((address_space(3))) unsigned*)l, 16, 0, 0);
}

// ---------------------------------------------------------------- fp32 -> bf16 (RNE)
__global__ __launch_bounds__(256) void f32_to_bf16(const float* __restrict__ src,
                                                   unsigned short* __restrict__ dst, int n4) {
    int i = blockIdx.x * 256 + threadIdx.x;
    int stride = gridDim.x * 256;
    for (; i < n4; i += stride) {
        float4 v = ((const float4*)src)[i];
        ushort4 o;
        o.x = f2bf(v.x); o.y = f2bf(v.y); o.z = f2bf(v.z); o.w = f2bf(v.w);
        ((ushort4*)dst)[i] = o;
    }
}

// ---------------------------------------------------------------- X = relu(emb[tok]) -> bf16
__global__ __launch_bounds__(256) void embed_relu_bf16(const int* __restrict__ target,
                                                       const float* __restrict__ emb,
                                                       unsigned short* __restrict__ X) {
    int bid = blockIdx.x;           // t*64 + b
    int t = bid >> 6, b = bid & 63;
    int tok = (t == 0) ? 0 : target[b * T_STEPS + (t - 1)];
    const float4* src = (const float4*)(emb + (size_t)tok * HID);
    float4 v = src[threadIdx.x];
    ushort4 o;
    o.x = f2bf(fmaxf(v.x, 0.f)); o.y = f2bf(fmaxf(v.y, 0.f));
    o.z = f2bf(fmaxf(v.z, 0.f)); o.w = f2bf(fmaxf(v.w, 0.f));
    ((ushort4*)(X + (size_t)bid * HID))[threadIdx.x] = o;
}

// ---------------------------------------------------------------- barrier counters init
__global__ void init_bar(unsigned int* bar) {
    if (threadIdx.x < 32) bar[threadIdx.x] = 0u;
}

// ---------------------------------------------------------------- gi GEMM
__global__ __launch_bounds__(256) void gemm_mfma_bt(const unsigned short* __restrict__ A,
                                                    const unsigned short* __restrict__ W,
                                                    const float* __restrict__ bias,
                                                    float* __restrict__ out,
                                                    int N, int K) {
    __shared__ unsigned short As[128 * 64];
    __shared__ unsigned short Bs[128 * 64];
    int tid  = threadIdx.x;
    int lane = tid & 63;
    int wid  = tid >> 6;
    int wm   = wid >> 1, wn = wid & 1;
    const int bM = blockIdx.y * 128;
    const int bN = blockIdx.x * 128;

    f32x4 acc[4][4];
#pragma unroll
    for (int i = 0; i < 4; ++i)
#pragma unroll
        for (int j = 0; j < 4; ++j) acc[i][j] = (f32x4){0.f, 0.f, 0.f, 0.f};

    int sr[4], sc[4];
#pragma unroll
    for (int q = 0; q < 4; ++q) {
        sr[q] = (wid * 4 + q) * 8 + (lane >> 3);
        sc[q] = (lane & 7) ^ (sr[q] & 7);
    }

    for (int kt = 0; kt < K; kt += 64) {
        __syncthreads();
#pragma unroll
        for (int q = 0; q < 4; ++q) {
            gld_lds16(A + (size_t)(bM + sr[q]) * K + kt + sc[q] * 8, As + (wid * 4 + q) * 512);
            gld_lds16(W + (size_t)(bN + sr[q]) * K + kt + sc[q] * 8, Bs + (wid * 4 + q) * 512);
        }
        __syncthreads();

#pragma unroll
        for (int ks = 0; ks < 2; ++ks) {
            bf16x8 a[4], b[4];
#pragma unroll
            for (int mf = 0; mf < 4; ++mf) {
                int r  = wm * 64 + mf * 16 + (lane & 15);
                int ch = (ks * 4 + (lane >> 4)) ^ (r & 7);
                a[mf] = *(const bf16x8*)(As + r * 64 + ch * 8);
            }
#pragma unroll
            for (int nf = 0; nf < 4; ++nf) {
                int r  = wn * 64 + nf * 16 + (lane & 15);
                int ch = (ks * 4 + (lane >> 4)) ^ (r & 7);
                b[nf] = *(const bf16x8*)(Bs + r * 64 + ch * 8);
            }
#pragma unroll
            for (int mf = 0; mf < 4; ++mf)
#pragma unroll
                for (int nf = 0; nf < 4; ++nf)
                    acc[mf][nf] = __builtin_amdgcn_mfma_f32_16x16x32_bf16(
                        a[mf], b[nf], acc[mf][nf], 0, 0, 0);
        }
    }

    int rif = (lane >> 4) * 4;
    int col = lane & 15;
#pragma unroll
    for (int mf = 0; mf < 4; ++mf) {
#pragma unroll
        for (int j = 0; j < 4; ++j) {
            int gr = bM + wm * 64 + mf * 16 + rif + j;
#pragma unroll
            for (int nf = 0; nf < 4; ++nf) {
                int gc = bN + wn * 64 + nf * 16 + col;
                out[(size_t)gr * N + gc] = acc[mf][nf][j] + bias[gc];
            }
        }
    }
}

// ---------------------------------------------------------------- logits GEMM + permute + softmax partials
__global__ __launch_bounds__(256) void gemm_logits(const unsigned short* __restrict__ A,
                                                   const unsigned short* __restrict__ W,
                                                   const float* __restrict__ bias,
                                                   float* __restrict__ out,
                                                   float2* __restrict__ pstat) {
    __shared__ unsigned short As[128 * 64];
    __shared__ unsigned short Bs[128 * 64];
    int bx = blockIdx.x;
    int by = blockIdx.y;
    const int bM = by * 128;
    const int bN = bx * 128;
    const int K = HID;

    int tid  = threadIdx.x;
    int lane = tid & 63;
    int wid  = tid >> 6;
    int wm   = wid >> 1, wn = wid & 1;

    f32x4 acc[4][4];
#pragma unroll
    for (int i = 0; i < 4; ++i)
#pragma unroll
        for (int j = 0; j < 4; ++j) acc[i][j] = (f32x4){0.f, 0.f, 0.f, 0.f};

    int sr[4], sc[4];
#pragma unroll
    for (int q = 0; q < 4; ++q) {
        sr[q] = (wid * 4 + q) * 8 + (lane >> 3);
        sc[q] = (lane & 7) ^ (sr[q] & 7);
    }

    for (int kt = 0; kt < K; kt += 64) {
        __syncthreads();
#pragma unroll
        for (int q = 0; q < 4; ++q) {
            gld_lds16(A + (size_t)(bM + sr[q]) * K + kt + sc[q] * 8, As + (wid * 4 + q) * 512);
            gld_lds16(W + (size_t)(bN + sr[q]) * K + kt + sc[q] * 8, Bs + (wid * 4 + q) * 512);
        }
        __syncthreads();

#pragma unroll
        for (int ks = 0; ks < 2; ++ks) {
            bf16x8 a[4], b[4];
#pragma unroll
            for (int mf = 0; mf < 4; ++mf) {
                int r  = wm * 64 + mf * 16 + (lane & 15);
                int ch = (ks * 4 + (lane >> 4)) ^ (r & 7);
                a[mf] = *(const bf16x8*)(As + r * 64 + ch * 8);
            }
#pragma unroll
            for (int nf = 0; nf < 4; ++nf) {
                int r  = wn * 64 + nf * 16 + (lane & 15);
                int ch = (ks * 4 + (lane >> 4)) ^ (r & 7);
                b[nf] = *(const bf16x8*)(Bs + r * 64 + ch * 8);
            }
#pragma unroll
            for (int mf = 0; mf < 4; ++mf)
#pragma unroll
                for (int nf = 0; nf < 4; ++nf)
                    acc[mf][nf] = __builtin_amdgcn_mfma_f32_16x16x32_bf16(
                        a[mf], b[nf], acc[mf][nf], 0, 0, 0);
        }
    }

    int rif = (lane >> 4) * 4;
    int col = lane & 15;
#pragma unroll
    for (int mf = 0; mf < 4; ++mf) {
#pragma unroll
        for (int j = 0; j < 4; ++j) {
            int gr = bM + wm * 64 + mf * 16 + rif + j;
            int t = gr >> 6, b = gr & 63;
            int prow = b * T_STEPS + t;
            float v[4];
            float mx = -1e30f;
#pragma unroll
            for (int nf = 0; nf < 4; ++nf) {
                int gc = bN + wn * 64 + nf * 16 + col;
                v[nf] = acc[mf][nf][j] + bias[gc];
                out[(size_t)prow * VOCABN + gc] = v[nf];
                mx = fmaxf(mx, v[nf]);
            }
#pragma unroll
            for (int off = 1; off < 16; off <<= 1) mx = fmaxf(mx, __shfl_xor(mx, off, 64));
            float se = 0.f;
#pragma unroll
            for (int nf = 0; nf < 4; ++nf) se += __expf(v[nf] - mx);
#pragma unroll
            for (int off = 1; off < 16; off <<= 1) se += __shfl_xor(se, off, 64);
            if (col == 0) pstat[(size_t)prow * NPART + bx * 2 + wn] = make_float2(mx, se);
        }
    }
}

// ---------------------------------------------------------------- persistent 30-step GRU
// 64 blocks x 256 threads (cooperative). Block owns m in [bid*16, bid*16+16).
// W panel LDS-resident for all steps (pre-swizzled fragment slots).
// h exchange via agent-scope atomics; custom per-step barrier (no cache-wide fences).
// MFMA operands: D[m x b] = W_frag x h_frag  -> thread owns (b, 4 consecutive m).
__global__ __launch_bounds__(256) void gru_persistent(
    const unsigned short* __restrict__ h0b,   // [64][1024] bf16
    const float* __restrict__ enc_h,          // [64][1024] fp32
    const unsigned short* __restrict__ Whh,   // [3072][1024] bf16
    const float* __restrict__ b_hh,
    const float* __restrict__ gi,             // [30][64][3072] fp32
    unsigned short* __restrict__ Hall,        // [30][64][1024] bf16
    float* __restrict__ h_final,              // [64][1024] fp32
    unsigned int* __restrict__ bar)           // [32] zeroed per launch
{
    __shared__ unsigned short Wlds[48 * 1024];   // 96 KB: slot[(kt*3+g)*64 + lane] = 8 bf16
    int tid  = threadIdx.x;
    int lane = tid & 63;
    int wq   = tid >> 6;            // batch quarter
    int l15  = lane & 15, l4 = lane >> 4;
    int m0   = blockIdx.x * 16;
    int b    = wq * 16 + l15;       // this thread's batch row (B-frag row & epilogue row)
    int mb   = m0 + l4 * 4;         // first of 4 consecutive m this thread owns

    // ---- one-time W panel load: slot-block sb in [0,96), kt = sb/3, g = sb%3
    for (int i = 0; i < 24; ++i) {
        int sb = wq * 24 + i;
        int kt = sb / 3, g = sb % 3;
        const unsigned short* src =
            Whh + (size_t)(g * HID + m0 + l15) * HID + kt * 32 + l4 * 8;
        gld_lds16(src, Wlds + sb * 512);
    }

    float hp[4];
    {
        float4 h4 = *(const float4*)(enc_h + (size_t)b * HID + mb);
        hp[0] = h4.x; hp[1] = h4.y; hp[2] = h4.z; hp[3] = h4.w;
    }
    float bhr[4], bhz[4], bhn[4];
    {
        float4 r4 = *(const float4*)(b_hh + mb);
        float4 z4 = *(const float4*)(b_hh + HID + mb);
        float4 n4 = *(const float4*)(b_hh + 2 * HID + mb);
        bhr[0]=r4.x; bhr[1]=r4.y; bhr[2]=r4.z; bhr[3]=r4.w;
        bhz[0]=z4.x; bhz[1]=z4.y; bhz[2]=z4.z; bhz[3]=z4.w;
        bhn[0]=n4.x; bhn[1]=n4.y; bhn[2]=n4.z; bhn[3]=n4.w;
    }
    __syncthreads();   // W panel ready (drains global_load_lds)

    for (int t = 0; t < T_STEPS; ++t) {
        const unsigned short* Asrc = (t == 0) ? h0b : (Hall + (size_t)(t - 1) * BATCH * HID);
        const unsigned long long* A8 = (const unsigned long long*)Asrc;
        size_t abase = (size_t)b * (HID / 4) + l4 * 2;   // ulong units

        // gi prefetch (independent of h)
        const float* gib = gi + (size_t)t * BATCH * G3 + (size_t)b * G3;
        float4 giR = *(const float4*)(gib + mb);
        float4 giZ = *(const float4*)(gib + HID + mb);
        float4 giN = *(const float4*)(gib + 2 * HID + mb);
        float gr4[4] = {giR.x, giR.y, giR.z, giR.w};
        float gz4[4] = {giZ.x, giZ.y, giZ.z, giZ.w};
        float gn4[4] = {giN.x, giN.y, giN.z, giN.w};

        f32x4 acc[3];
#pragma unroll
        for (int g = 0; g < 3; ++g) acc[g] = (f32x4){0.f, 0.f, 0.f, 0.f};

#pragma unroll 8
        for (int kt = 0; kt < 32; ++kt) {
            unsigned long long lo = __hip_atomic_load(A8 + abase + (size_t)kt * 8,
                                                      __ATOMIC_RELAXED, __HIP_MEMORY_SCOPE_AGENT);
            unsigned long long hi = __hip_atomic_load(A8 + abase + (size_t)kt * 8 + 1,
                                                      __ATOMIC_RELAXED, __HIP_MEMORY_SCOPE_AGENT);
            union { unsigned long long u[2]; bf16x8 v; } hb;
            hb.u[0] = lo; hb.u[1] = hi;
#pragma unroll
            for (int g = 0; g < 3; ++g) {
                bf16x8 wfrag = *(const bf16x8*)(Wlds + ((size_t)(kt * 3 + g) * 64 + lane) * 8);
                acc[g] = __builtin_amdgcn_mfma_f32_16x16x32_bf16(wfrag, hb.v, acc[g], 0, 0, 0);
            }
        }

        // epilogue: thread owns (b, mb..mb+3)
        unsigned long long pack = 0;
#pragma unroll
        for (int j = 0; j < 4; ++j) {
            float r = 1.f / (1.f + __expf(-(gr4[j] + acc[0][j] + bhr[j])));
            float z = 1.f / (1.f + __expf(-(gz4[j] + acc[1][j] + bhz[j])));
            float e2 = __expf(2.f * (gn4[j] + r * (acc[2][j] + bhn[j])));
            float n = 1.f - 2.f / (e2 + 1.f);   // tanh
            float hnew = (1.f - z) * n + z * hp[j];
            hp[j] = hnew;
            pack |= (unsigned long long)f2bf(hnew) << (16 * j);
        }
        __hip_atomic_store((unsigned long long*)(Hall + (size_t)t * BATCH * HID +
                                                 (size_t)b * HID + mb),
                           pack, __ATOMIC_RELAXED, __HIP_MEMORY_SCOPE_AGENT);
        if (t == T_STEPS - 1) {
            float4 hf = {hp[0], hp[1], hp[2], hp[3]};
            *(float4*)(h_final + (size_t)b * HID + mb) = hf;
        }

        if (t < T_STEPS - 1) {
            __syncthreads();   // all threads' agent stores drained (vmcnt(0) before barrier)
            if (tid == 0) {
                __hip_atomic_fetch_add(bar + t, 1u, __ATOMIC_ACQ_REL, __HIP_MEMORY_SCOPE_AGENT);
                while (__hip_atomic_load(bar + t, __ATOMIC_ACQUIRE,
                                         __HIP_MEMORY_SCOPE_AGENT) < 64u)
                    __builtin_amdgcn_s_sleep(2);
            }
            __syncthreads();
        }
    }
}

// ---------------------------------------------------------------- softmax partial reduce
__global__ __launch_bounds__(64) void lsm_reduce(const float2* __restrict__ pstat,
                                                 float2* __restrict__ stats) {
    int lane = threadIdx.x;
    const float2* p = pstat + (size_t)blockIdx.x * NPART;
    float m = -1e30f;
    for (int i = lane; i < NPART; i += 64) m = fmaxf(m, p[i].x);
#pragma unroll
    for (int off = 1; off < 64; off <<= 1) m = fmaxf(m, __shfl_xor(m, off, 64));
    float s = 0.f;
    for (int i = lane; i < NPART; i += 64) { float2 t = p[i]; s += t.y * __expf(t.x - m); }
#pragma unroll
    for (int off = 1; off < 64; off <<= 1) s += __shfl_xor(s, off, 64);
    if (lane == 0) stats[blockIdx.x] = make_float2(m, logf(s));
}

// ---------------------------------------------------------------- apply: out -= mx + logZ
__global__ __launch_bounds__(256) void lsm_apply(float* __restrict__ out,
                                                 const float2* __restrict__ stats) {
    int i = blockIdx.x * 256 + threadIdx.x;
    int stride = gridDim.x * 256;
    const int total4 = ROWS * VOCABN / 4;
    for (; i < total4; i += stride) {
        int row = i / (VOCABN / 4);
        float2 st = stats[row];
        float c = st.x + st.y;
        float4 v = ((float4*)out)[i];
        v.x -= c; v.y -= c; v.z -= c; v.w -= c;
        ((float4*)out)[i] = v;
    }
}

// ----------------------------------------------------------------
extern "C" void kernel_launch(void* const* d_in, const int* in_sizes, int n_in,
                              void* d_out, int out_size, void* d_ws, size_t ws_size,
                              hipStream_t stream) {
    const float* enc_h  = (const float*)d_in[1];
    const int*   target = (const int*)d_in[2];
    const float* emb    = (const float*)d_in[3];
    const float* w_ih   = (const float*)d_in[4];
    const float* w_hh   = (const float*)d_in[5];
    const float* b_ih   = (const float*)d_in[6];
    const float* b_hh   = (const float*)d_in[7];
    const float* out_w  = (const float*)d_in[8];
    const float* out_b  = (const float*)d_in[9];
    float* out = (float*)d_out;

    char* p = (char*)d_ws;
    unsigned short* Xb   = (unsigned short*)p; p += (size_t)ROWS * HID * 2;
    unsigned short* Wih  = (unsigned short*)p; p += (size_t)G3 * HID * 2;
    unsigned short* OutW = (unsigned short*)p; p += (size_t)VOCABN * HID * 2;
    unsigned short* Hall = (unsigned short*)p; p += (size_t)ROWS * HID * 2;
    float* gi   = (float*)p; p += (size_t)ROWS * G3 * 4;
    unsigned short* Whhb = (unsigned short*)p; p += (size_t)G3 * HID * 2;
    unsigned short* h0b  = (unsigned short*)p; p += (size_t)BATCH * HID * 2;
    float2* stats = (float2*)p; p += (size_t)ROWS * 8;
    unsigned int* bar = (unsigned int*)p; p += 32 * sizeof(unsigned int);
    float2* pstat = (float2*)Xb;   // overlays Xb+Wih (dead after gi GEMM)

    f32_to_bf16<<<768, 256, 0, stream>>>(w_ih, Wih, G3 * HID / 4);
    f32_to_bf16<<<768, 256, 0, stream>>>(w_hh, Whhb, G3 * HID / 4);
    f32_to_bf16<<<2048, 256, 0, stream>>>(out_w, OutW, VOCABN * HID / 4);
    f32_to_bf16<<<64, 256, 0, stream>>>(enc_h, h0b, BATCH * HID / 4);
    embed_relu_bf16<<<ROWS, 256, 0, stream>>>(target, emb, Xb);
    init_bar<<<1, 64, 0, stream>>>(bar);

    gemm_mfma_bt<<<dim3(G3 / 128, ROWS / 128), 256, 0, stream>>>(Xb, Wih, b_ih, gi, G3, HID);

    {
        const unsigned short* a0 = h0b;
        const float* a1 = enc_h;
        const unsigned short* a2 = Whhb;
        const float* a3 = b_hh;
        const float* a4 = gi;
        unsigned short* a5 = Hall;
        float* a6 = out + OUT_HID_OFF;
        unsigned int* a7 = bar;
        void* args[] = {&a0, &a1, &a2, &a3, &a4, &a5, &a6, &a7};
        hipLaunchCooperativeKernel((void*)gru_persistent, dim3(64), dim3(256),
                                   args, 0, stream);
    }

    gemm_logits<<<dim3(NBX, NBY), 256, 0, stream>>>(Hall, OutW, out_b, out, pstat);
    lsm_reduce<<<ROWS, 64, 0, stream>>>(pstat, stats);
    lsm_apply<<<2048, 256, 0, stream>>>(out, stats);
}